// Round 8
// baseline (483.372 us; speedup 1.0000x reference)
//
#include <hip/hip_runtime.h>
#include <math.h>

#define HH 7
#define WW 7
#define CC 512
#define HF 64
#define WF 256
#define NS 49            // HH*WW
#define ROWS4 (CC / 4)   // float4 elements per spatial row of transposed feats
#define NSUB 8           // sub-chunks per wave (128 ch / 16)
#define TSTR 50          // private tile stride (49 + 1 pad)
#define NBINS 2048       // 32 y-bands x 64 x-bins (serpentine)

typedef float floatv4 __attribute__((ext_vector_type(4)));  // native vec for NT store

// Transpose feats (C, HF*WF) -> ws (HF*WF, C) so channel gathers coalesce.
__global__ __launch_bounds__(256) void transpose_feats(const float* __restrict__ in,
                                                       float* __restrict__ out) {
    __shared__ float tile[32][33];
    const int P = HF * WF;  // 16384
    int p  = blockIdx.x * 32 + threadIdx.x;  // spatial index
    int cb = blockIdx.y * 32;                // channel base
#pragma unroll
    for (int r = 0; r < 32; r += 8)
        tile[threadIdx.y + r][threadIdx.x] = in[(size_t)(cb + threadIdx.y + r) * P + p];
    __syncthreads();
    int c  = cb + threadIdx.x;
    int pb = blockIdx.x * 32;
#pragma unroll
    for (int r = 0; r < 32; r += 8)
        out[(size_t)(pb + threadIdx.y + r) * CC + c] = tile[threadIdx.x][threadIdx.y + r];
}

// Spatial bin key: serpentine over (y-band, x-bin).
__device__ __forceinline__ int box_key(const float* __restrict__ boxes, int b,
                                       float sy, float sx) {
    float xc = boxes[b * 4 + 0];
    float yc = boxes[b * 4 + 1];
    int yb = (int)(yc * sy);
    int xb = (int)(xc * sx);
    yb = min(max(yb, 0), 31);
    xb = min(max(xb, 0), 63);
    if (yb & 1) xb = 63 - xb;          // serpentine
    return (yb << 6) | xb;
}

// ---- Parallel permutation build ----
__global__ __launch_bounds__(256) void hist_zero(int* __restrict__ hist) {
    hist[blockIdx.x * 256 + threadIdx.x] = 0;
}

__global__ __launch_bounds__(256) void hist_count(const float* __restrict__ boxes,
                                                  const int* __restrict__ ih_p,
                                                  const int* __restrict__ iw_p,
                                                  int B, int* __restrict__ hist) {
    int b = blockIdx.x * 256 + threadIdx.x;
    if (b < B) {
        float sy = 32.0f / (float)ih_p[0];
        float sx = 64.0f / (float)iw_p[0];
        atomicAdd(&hist[box_key(boxes, b, sy, sx)], 1);   // device-scope by default
    }
}

// Exclusive prefix sum over NBINS global ints (1 block, 2048 elems).
__global__ __launch_bounds__(256) void hist_scan(int* __restrict__ hist) {
    __shared__ int part[256];
    const int tid  = threadIdx.x;
    const int base = tid * (NBINS / 256);
    int v[NBINS / 256];
    int s = 0;
#pragma unroll
    for (int i = 0; i < NBINS / 256; ++i) { v[i] = s; s += hist[base + i]; }
    part[tid] = s;
    __syncthreads();
    for (int d = 1; d < 256; d <<= 1) {
        int t = (tid >= d) ? part[tid - d] : 0;
        __syncthreads();
        part[tid] += t;
        __syncthreads();
    }
    const int off = part[tid] - s;   // exclusive prefix of this thread's total
#pragma unroll
    for (int i = 0; i < NBINS / 256; ++i) hist[base + i] = v[i] + off;
}

__global__ __launch_bounds__(256) void scatter_perm(const float* __restrict__ boxes,
                                                    const int* __restrict__ ih_p,
                                                    const int* __restrict__ iw_p,
                                                    int B, int* __restrict__ hist,
                                                    int* __restrict__ perm) {
    int b = blockIdx.x * 256 + threadIdx.x;
    if (b < B) {
        float sy = 32.0f / (float)ih_p[0];
        float sx = 64.0f / (float)iw_p[0];
        int pos = atomicAdd(&hist[box_key(boxes, b, sy, sx)], 1);
        perm[pos] = b;
    }
}

__device__ __forceinline__ void box_setup(int s, int b,
                                          const float* __restrict__ boxes,
                                          const int* __restrict__ ih_p,
                                          const int* __restrict__ iw_p,
                                          int4* o_out, float4* w_out) {
    int i = s / WW;
    int j = s - i * WW;
    float IW1 = (float)(iw_p[0] - 1);
    float IH1 = (float)(ih_p[0] - 1);
    float xc = boxes[b * 4 + 0];
    float yc = boxes[b * 4 + 1];
    float bw = boxes[b * 4 + 2];
    float bh = boxes[b * 4 + 3];
    float inv_w = 1.0f / IW1;
    float inv_h = 1.0f / IH1;
    float tx = (float)(j - 3) * (1.0f / 3.0f);
    float ty = (float)(i - 3) * (1.0f / 3.0f);
    float gx = (2.0f * xc - IW1) * inv_w + (bw * inv_w) * tx;
    float gy = (2.0f * yc - IH1) * inv_h + (bh * inv_h) * ty;
    float px = (gx + 1.0f) * 0.5f * (float)(WF - 1);
    float py = (gy + 1.0f) * 0.5f * (float)(HF - 1);

    float x0f = floorf(px), y0f = floorf(py);
    float wx1 = px - x0f, wx0 = 1.0f - wx1;
    float wy1 = py - y0f, wy0 = 1.0f - wy1;
    float x1f = x0f + 1.0f, y1f = y0f + 1.0f;

    bool vx0 = (x0f >= 0.0f) && (x0f <= (float)(WF - 1));
    bool vx1 = (x1f >= 0.0f) && (x1f <= (float)(WF - 1));
    bool vy0 = (y0f >= 0.0f) && (y0f <= (float)(HF - 1));
    bool vy1 = (y1f >= 0.0f) && (y1f <= (float)(HF - 1));

    int xi0 = (int)fminf(fmaxf(x0f, 0.0f), (float)(WF - 1));
    int xi1 = (int)fminf(fmaxf(x1f, 0.0f), (float)(WF - 1));
    int yi0 = (int)fminf(fmaxf(y0f, 0.0f), (float)(HF - 1));
    int yi1 = (int)fminf(fmaxf(y1f, 0.0f), (float)(HF - 1));

    int4 o;
    o.x = yi0 * WF + xi0;
    o.y = yi0 * WF + xi1;
    o.z = yi1 * WF + xi0;
    o.w = yi1 * WF + xi1;
    float4 w4;
    w4.x = wx0 * wy0 * ((vx0 && vy0) ? 1.0f : 0.0f);
    w4.y = wx1 * wy0 * ((vx1 && vy0) ? 1.0f : 0.0f);
    w4.z = wx0 * wy1 * ((vx0 && vy1) ? 1.0f : 0.0f);
    w4.w = wx1 * wy1 * ((vx1 && vy1) ? 1.0f : 0.0f);
    *o_out = o;
    *w_out = w4;
}

// One block per box (via perm + bijective XCD chunking). src = transposed feats.
// v9: ZERO-SYNC WAVES. Each wave owns a private 16-channel sub-tile (3.2 KB);
// 8 sub-chunks of 16 channels per wave, no __syncthreads in the main loop.
// The compiler can use counted vmcnt/lgkmcnt instead of barrier-forced full
// drains; sub-chunk q+1's loads stay in flight under q's NT-store phase.
__global__ __launch_bounds__(256) void roi_pool_v9(const float* __restrict__ src,
                                                   const float* __restrict__ boxes,
                                                   const int* __restrict__ ih_p,
                                                   const int* __restrict__ iw_p,
                                                   const int* __restrict__ perm,
                                                   float* __restrict__ out) {
    __shared__ int4   s_off[NS];          // float4-row base: cell*ROWS4
    __shared__ float4 s_wt[NS];
    __shared__ float  tile[4][16 * TSTR]; // per-wave private sub-tiles

    const int nwg  = gridDim.x;
    const int bid  = blockIdx.x;
    const int q_   = nwg >> 3, r_ = nwg & 7;
    const int xcd  = bid & 7, slot = bid >> 3;
    const int rank = xcd * q_ + min(xcd, r_) + slot;
    const int b    = perm[rank];

    const int tid = threadIdx.x;
    const int wid = tid >> 6;   // wave 0..3 -> channels [wid*128, wid*128+128)
    const int l   = tid & 63;
    const int g   = l & 3;      // float4 group within 16-ch sub-chunk
    const int ph  = l >> 2;     // sample phase 0..15

    if (tid < NS) {
        int4 o; float4 w4;
        box_setup(tid, b, boxes, ih_p, iw_p, &o, &w4);
        o.x *= ROWS4; o.y *= ROWS4; o.z *= ROWS4; o.w *= ROWS4;
        s_off[tid] = o;
        s_wt[tid]  = w4;
    }
    __syncthreads();   // the ONLY block-wide barrier

    // Hoist per-sample constants into registers (static unroll).
    int4   o_r[4];
    float4 w_r[4];
#pragma unroll
    for (int it = 0; it < 4; ++it) {
        int s = ph + (it << 4);
        if (s < NS) {
            o_r[it] = s_off[s];
            w_r[it] = s_wt[s];
        }
    }

    const size_t  outbase = (size_t)b * (CC * NS);
    const float4* src4    = (const float4*)src;
    float*        mytile  = &tile[wid][0];
    const int     wc4     = wid << 5;   // wave channel base in float4 units

    float4 A_[4], B_[4], C_[4], D_[4];  // prefetched corner slices (static idx)

    // issue 16 corner loads for sub-chunk q (16 channels = 4 float4)
#define LOADS(qq)                                                           \
    do {                                                                    \
        const int cb4_ = wc4 + ((qq) << 2);                                 \
        _Pragma("unroll")                                                   \
        for (int it = 0; it < 4; ++it) {                                    \
            int s_ = ph + (it << 4);                                        \
            if (s_ < NS) {                                                  \
                int4 o_ = o_r[it];                                          \
                A_[it] = src4[o_.x + cb4_ + g];                             \
                B_[it] = src4[o_.y + cb4_ + g];                             \
                C_[it] = src4[o_.z + cb4_ + g];                             \
                D_[it] = src4[o_.w + cb4_ + g];                             \
            }                                                               \
        }                                                                   \
    } while (0)

    // FMA prefetched values + write private tile rows (4g+j)*TSTR + s
#define FMAST()                                                             \
    do {                                                                    \
        _Pragma("unroll")                                                   \
        for (int it = 0; it < 4; ++it) {                                    \
            int s_ = ph + (it << 4);                                        \
            if (s_ < NS) {                                                  \
                float4 w_ = w_r[it];                                        \
                int a0 = 200 * g + s_;   /* (4g)*TSTR + s */                \
                mytile[a0      ] = A_[it].x * w_.x + B_[it].x * w_.y + C_[it].x * w_.z + D_[it].x * w_.w; \
                mytile[a0 +  50] = A_[it].y * w_.x + B_[it].y * w_.y + C_[it].y * w_.z + D_[it].y * w_.w; \
                mytile[a0 + 100] = A_[it].z * w_.x + B_[it].z * w_.y + C_[it].z * w_.z + D_[it].z * w_.w; \
                mytile[a0 + 150] = A_[it].w * w_.x + B_[it].w * w_.y + C_[it].w * w_.z + D_[it].w * w_.w; \
            }                                                               \
        }                                                                   \
    } while (0)

    // read private tile in output order, coalesced NT stores (196 float4)
#define WRITEPH(qq)                                                         \
    do {                                                                    \
        float* outc_ = out + outbase + (size_t)((wid << 7) + ((qq) << 4)) * NS; \
        _Pragma("unroll")                                                   \
        for (int m = 0; m < 4; ++m) {                                       \
            int k4 = l + (m << 6);                                          \
            if (k4 < (16 * NS) / 4) {                                       \
                int e_ = k4 << 2;                                           \
                int c_ = e_ / NS;                                           \
                int s_ = e_ - c_ * NS;                                      \
                floatv4 v_;                                                 \
                v_.x = mytile[c_ * TSTR + s_];                              \
                if (++s_ == NS) { s_ = 0; ++c_; }                           \
                v_.y = mytile[c_ * TSTR + s_];                              \
                if (++s_ == NS) { s_ = 0; ++c_; }                           \
                v_.z = mytile[c_ * TSTR + s_];                              \
                if (++s_ == NS) { s_ = 0; ++c_; }                           \
                v_.w = mytile[c_ * TSTR + s_];                              \
                __builtin_nontemporal_store(v_, (floatv4*)outc_ + k4);      \
            }                                                               \
        }                                                                   \
    } while (0)

    LOADS(0);
    for (int q = 0; q < NSUB; ++q) {
        FMAST();                      // consume A_..D_ into private tile
        if (q + 1 < NSUB) LOADS(q + 1);  // refill; stays in flight under stores
        WRITEPH(q);                   // lgkmcnt-ordered tile reads + NT stores
    }

#undef LOADS
#undef FMAST
#undef WRITEPH
}

// Fallback (ws too small for transpose): original scalar path on raw feats.
__global__ __launch_bounds__(256) void roi_pool_fb(const float* __restrict__ src,
                                                   const float* __restrict__ boxes,
                                                   const int* __restrict__ ih_p,
                                                   const int* __restrict__ iw_p,
                                                   float* __restrict__ out) {
    __shared__ int4   s_off[NS];
    __shared__ float4 s_wt[NS];
    __shared__ float  tile[NS * 257];

    const int b   = blockIdx.x;
    const int tid = threadIdx.x;

    if (tid < NS) {
        int4 o; float4 w4;
        box_setup(tid, b, boxes, ih_p, iw_p, &o, &w4);
        s_off[tid] = o;
        s_wt[tid]  = w4;
    }
    __syncthreads();

    const size_t outbase = (size_t)b * (CC * NS);
    for (int c0 = 0; c0 < CC; c0 += 256) {
        const int cterm = (c0 + tid) * (HF * WF);
        for (int s = 0; s < NS; ++s) {
            int4   o = s_off[s];
            float4 w = s_wt[s];
            float v = src[o.x + cterm] * w.x + src[o.y + cterm] * w.y +
                      src[o.z + cterm] * w.z + src[o.w + cterm] * w.w;
            tile[s * 257 + tid] = v;
        }
        __syncthreads();
        const size_t ob = outbase + (size_t)c0 * NS;
        for (int k = tid; k < 256 * NS; k += 256) {
            int cl = k / NS;
            int s  = k - cl * NS;
            out[ob + k] = tile[s * 257 + cl];
        }
        __syncthreads();
    }
}

extern "C" void kernel_launch(void* const* d_in, const int* in_sizes, int n_in,
                              void* d_out, int out_size, void* d_ws, size_t ws_size,
                              hipStream_t stream) {
    const float* feats = (const float*)d_in[0];
    const float* boxes = (const float*)d_in[1];
    const int*   ih    = (const int*)d_in[2];
    const int*   iw    = (const int*)d_in[3];
    float*       out   = (float*)d_out;
    const int B = in_sizes[1] / 4;

    const size_t tf_bytes = (size_t)CC * HF * WF * sizeof(float);  // 32 MiB
    const size_t need = tf_bytes + (size_t)B * sizeof(int) + (size_t)NBINS * sizeof(int);
    if (ws_size >= need) {
        float* tf   = (float*)d_ws;
        int*   perm = (int*)((char*)d_ws + tf_bytes);
        int*   hist = (int*)((char*)d_ws + tf_bytes + (size_t)B * sizeof(int));
        dim3 tb(32, 8);
        dim3 tg((HF * WF) / 32, CC / 32);
        transpose_feats<<<tg, tb, 0, stream>>>(feats, tf);
        hist_zero<<<NBINS / 256, 256, 0, stream>>>(hist);
        hist_count<<<(B + 255) / 256, 256, 0, stream>>>(boxes, ih, iw, B, hist);
        hist_scan<<<1, 256, 0, stream>>>(hist);
        scatter_perm<<<(B + 255) / 256, 256, 0, stream>>>(boxes, ih, iw, B, hist, perm);
        roi_pool_v9<<<B, 256, 0, stream>>>(tf, boxes, ih, iw, perm, out);
    } else {
        roi_pool_fb<<<B, 256, 0, stream>>>(feats, boxes, ih, iw, out);
    }
}

// Round 9
// 455.453 us; speedup vs baseline: 1.0613x; 1.0613x over previous
//
#include <hip/hip_runtime.h>
#include <math.h>

#define HH 7
#define WW 7
#define CC 512
#define HF 64
#define WF 256
#define NS 49            // HH*WW
#define CHUNK 64         // channels per block (channel-sliced grid)
#define NSLICE (CC / CHUNK)      // 8
#define ROWS4 (CC / 4)   // float4 elements per spatial row of transposed feats
#define NE4 ((CHUNK * NS) / 4)   // 784 float4 outputs per block
#define NBINS 2048       // 32 y-bands x 64 x-bins (serpentine)

typedef float floatv4 __attribute__((ext_vector_type(4)));  // native vec for NT store

// Transpose feats (C, HF*WF) -> ws (HF*WF, C) so channel gathers coalesce.
__global__ __launch_bounds__(256) void transpose_feats(const float* __restrict__ in,
                                                       float* __restrict__ out) {
    __shared__ float tile[32][33];
    const int P = HF * WF;  // 16384
    int p  = blockIdx.x * 32 + threadIdx.x;  // spatial index
    int cb = blockIdx.y * 32;                // channel base
#pragma unroll
    for (int r = 0; r < 32; r += 8)
        tile[threadIdx.y + r][threadIdx.x] = in[(size_t)(cb + threadIdx.y + r) * P + p];
    __syncthreads();
    int c  = cb + threadIdx.x;
    int pb = blockIdx.x * 32;
#pragma unroll
    for (int r = 0; r < 32; r += 8)
        out[(size_t)(pb + threadIdx.y + r) * CC + c] = tile[threadIdx.x][threadIdx.y + r];
}

// Spatial bin key: serpentine over (y-band, x-bin).
__device__ __forceinline__ int box_key(const float* __restrict__ boxes, int b,
                                       float sy, float sx) {
    float xc = boxes[b * 4 + 0];
    float yc = boxes[b * 4 + 1];
    int yb = (int)(yc * sy);
    int xb = (int)(xc * sx);
    yb = min(max(yb, 0), 31);
    xb = min(max(xb, 0), 63);
    if (yb & 1) xb = 63 - xb;          // serpentine
    return (yb << 6) | xb;
}

// ---- Parallel permutation build ----
__global__ __launch_bounds__(256) void hist_zero(int* __restrict__ hist) {
    hist[blockIdx.x * 256 + threadIdx.x] = 0;
}

__global__ __launch_bounds__(256) void hist_count(const float* __restrict__ boxes,
                                                  const int* __restrict__ ih_p,
                                                  const int* __restrict__ iw_p,
                                                  int B, int* __restrict__ hist) {
    int b = blockIdx.x * 256 + threadIdx.x;
    if (b < B) {
        float sy = 32.0f / (float)ih_p[0];
        float sx = 64.0f / (float)iw_p[0];
        atomicAdd(&hist[box_key(boxes, b, sy, sx)], 1);   // device-scope by default
    }
}

// Exclusive prefix sum over NBINS global ints (1 block, 2048 elems).
__global__ __launch_bounds__(256) void hist_scan(int* __restrict__ hist) {
    __shared__ int part[256];
    const int tid  = threadIdx.x;
    const int base = tid * (NBINS / 256);
    int v[NBINS / 256];
    int s = 0;
#pragma unroll
    for (int i = 0; i < NBINS / 256; ++i) { v[i] = s; s += hist[base + i]; }
    part[tid] = s;
    __syncthreads();
    for (int d = 1; d < 256; d <<= 1) {
        int t = (tid >= d) ? part[tid - d] : 0;
        __syncthreads();
        part[tid] += t;
        __syncthreads();
    }
    const int off = part[tid] - s;   // exclusive prefix of this thread's total
#pragma unroll
    for (int i = 0; i < NBINS / 256; ++i) hist[base + i] = v[i] + off;
}

__global__ __launch_bounds__(256) void scatter_perm(const float* __restrict__ boxes,
                                                    const int* __restrict__ ih_p,
                                                    const int* __restrict__ iw_p,
                                                    int B, int* __restrict__ hist,
                                                    int* __restrict__ perm) {
    int b = blockIdx.x * 256 + threadIdx.x;
    if (b < B) {
        float sy = 32.0f / (float)ih_p[0];
        float sx = 64.0f / (float)iw_p[0];
        int pos = atomicAdd(&hist[box_key(boxes, b, sy, sx)], 1);
        perm[pos] = b;
    }
}

__device__ __forceinline__ void box_setup(int s, int b,
                                          const float* __restrict__ boxes,
                                          const int* __restrict__ ih_p,
                                          const int* __restrict__ iw_p,
                                          int4* o_out, float4* w_out) {
    int i = s / WW;
    int j = s - i * WW;
    float IW1 = (float)(iw_p[0] - 1);
    float IH1 = (float)(ih_p[0] - 1);
    float xc = boxes[b * 4 + 0];
    float yc = boxes[b * 4 + 1];
    float bw = boxes[b * 4 + 2];
    float bh = boxes[b * 4 + 3];
    float inv_w = 1.0f / IW1;
    float inv_h = 1.0f / IH1;
    float tx = (float)(j - 3) * (1.0f / 3.0f);
    float ty = (float)(i - 3) * (1.0f / 3.0f);
    float gx = (2.0f * xc - IW1) * inv_w + (bw * inv_w) * tx;
    float gy = (2.0f * yc - IH1) * inv_h + (bh * inv_h) * ty;
    float px = (gx + 1.0f) * 0.5f * (float)(WF - 1);
    float py = (gy + 1.0f) * 0.5f * (float)(HF - 1);

    float x0f = floorf(px), y0f = floorf(py);
    float wx1 = px - x0f, wx0 = 1.0f - wx1;
    float wy1 = py - y0f, wy0 = 1.0f - wy1;
    float x1f = x0f + 1.0f, y1f = y0f + 1.0f;

    bool vx0 = (x0f >= 0.0f) && (x0f <= (float)(WF - 1));
    bool vx1 = (x1f >= 0.0f) && (x1f <= (float)(WF - 1));
    bool vy0 = (y0f >= 0.0f) && (y0f <= (float)(HF - 1));
    bool vy1 = (y1f >= 0.0f) && (y1f <= (float)(HF - 1));

    int xi0 = (int)fminf(fmaxf(x0f, 0.0f), (float)(WF - 1));
    int xi1 = (int)fminf(fmaxf(x1f, 0.0f), (float)(WF - 1));
    int yi0 = (int)fminf(fmaxf(y0f, 0.0f), (float)(HF - 1));
    int yi1 = (int)fminf(fmaxf(y1f, 0.0f), (float)(HF - 1));

    int4 o;
    o.x = yi0 * WF + xi0;
    o.y = yi0 * WF + xi1;
    o.z = yi1 * WF + xi0;
    o.w = yi1 * WF + xi1;
    float4 w4;
    w4.x = wx0 * wy0 * ((vx0 && vy0) ? 1.0f : 0.0f);
    w4.y = wx1 * wy0 * ((vx1 && vy0) ? 1.0f : 0.0f);
    w4.z = wx0 * wy1 * ((vx0 && vy1) ? 1.0f : 0.0f);
    w4.w = wx1 * wy1 * ((vx1 && vy1) ? 1.0f : 0.0f);
    *o_out = o;
    *w_out = w4;
}

// Channel-sliced gather: grid = NSLICE * B blocks; each block = one (box, 64-ch
// slice). Per-XCD dispatch order is slice-major/rank-minor, so the concurrent
// window on an XCD = ~256 sorted neighbor boxes x 256 B/cell ~= 2.5 MB < 4 MB L2
// -> cross-block duplicate corner reads become L2 hits instead of L3 traffic.
// Per-block machine = v7's proven single-chunk structure (0 LDS conflicts).
// LDS layout: addr(s,c) = c*64 + (sigma(s) ^ (c>>2)),  sigma(s) = (s>>2)|((s&3)<<4).
__global__ __launch_bounds__(256) void roi_pool_v10(const float* __restrict__ src,
                                                    const float* __restrict__ boxes,
                                                    const int* __restrict__ ih_p,
                                                    const int* __restrict__ iw_p,
                                                    const int* __restrict__ perm,
                                                    int B,
                                                    float* __restrict__ out) {
    __shared__ int4   s_off[NS];   // float4-row base: cell*ROWS4
    __shared__ float4 s_wt[NS];
    __shared__ float  tile[CHUNK * 64];  // 16 KB, XOR-swizzled

    const int bid = blockIdx.x;
    int slice, rank;
    if ((B & 7) == 0) {
        // slice-major within each XCD's contiguous rank band
        const int xcd = bid & 7;
        const int seq = bid >> 3;        // 0..B-1 per xcd
        const int per = B >> 3;          // ranks per xcd
        slice = seq / per;
        rank  = xcd * per + (seq - slice * per);
    } else {
        slice = bid % NSLICE;            // fallback: correct, less optimal order
        rank  = bid / NSLICE;
    }
    const int b = perm[rank];

    const int tid = threadIdx.x;
    const int g   = tid & 15;   // float4 channel-group within 64-ch slice (c>>2)
    const int ph  = tid >> 4;   // sample phase 0..15

    if (tid < NS) {
        int4 o; float4 w4;
        box_setup(tid, b, boxes, ih_p, iw_p, &o, &w4);
        o.x *= ROWS4; o.y *= ROWS4; o.z *= ROWS4; o.w *= ROWS4;
        s_off[tid] = o;
        s_wt[tid]  = w4;
    }
    __syncthreads();

    const size_t outbase = (size_t)b * (CC * NS);
    const float4* src4   = (const float4*)src;
    const int cb4        = slice << 4;   // slice channel base in float4 units

    // ---- compute phase: 16 lanes = one sample (256B slice), 16 phases ----
#pragma unroll
    for (int it = 0; it < 4; ++it) {
        int s = ph + (it << 4);
        if (s < NS) {
            int4   o = s_off[s];
            float4 w = s_wt[s];
            float4 a  = src4[o.x + cb4 + g];
            float4 bb = src4[o.y + cb4 + g];
            float4 c  = src4[o.z + cb4 + g];
            float4 d  = src4[o.w + cb4 + g];
            int base = g << 8;              // c_local=4g -> c*64
            int sig  = (s >> 2) | ((s & 3) << 4);
            int sw   = sig ^ g;
            tile[base +       sw] = a.x * w.x + bb.x * w.y + c.x * w.z + d.x * w.w;
            tile[base +  64 + sw] = a.y * w.x + bb.y * w.y + c.y * w.z + d.y * w.w;
            tile[base + 128 + sw] = a.z * w.x + bb.z * w.y + c.z * w.z + d.z * w.w;
            tile[base + 192 + sw] = a.w * w.x + bb.w * w.y + c.w * w.z + d.w * w.w;
        }
    }
    __syncthreads();

    // ---- write phase: lane = output order (coalesced float4 NT stores) ----
    float* outc = out + outbase + (size_t)(slice * CHUNK) * NS;
    for (int k4 = tid; k4 < NE4; k4 += 256) {
        int e = k4 << 2;
        int c = e / NS;          // compiler magic-mul
        int s = e - c * NS;
        floatv4 v;
        v.x = tile[(c << 6) + (((s >> 2) | ((s & 3) << 4)) ^ (c >> 2))];
        if (++s == NS) { s = 0; ++c; }
        v.y = tile[(c << 6) + (((s >> 2) | ((s & 3) << 4)) ^ (c >> 2))];
        if (++s == NS) { s = 0; ++c; }
        v.z = tile[(c << 6) + (((s >> 2) | ((s & 3) << 4)) ^ (c >> 2))];
        if (++s == NS) { s = 0; ++c; }
        v.w = tile[(c << 6) + (((s >> 2) | ((s & 3) << 4)) ^ (c >> 2))];
        __builtin_nontemporal_store(v, (floatv4*)outc + k4);
    }
}

// Fallback (ws too small for transpose): original scalar path on raw feats.
__global__ __launch_bounds__(256) void roi_pool_fb(const float* __restrict__ src,
                                                   const float* __restrict__ boxes,
                                                   const int* __restrict__ ih_p,
                                                   const int* __restrict__ iw_p,
                                                   float* __restrict__ out) {
    __shared__ int4   s_off[NS];
    __shared__ float4 s_wt[NS];
    __shared__ float  tile[NS * 257];

    const int b   = blockIdx.x;
    const int tid = threadIdx.x;

    if (tid < NS) {
        int4 o; float4 w4;
        box_setup(tid, b, boxes, ih_p, iw_p, &o, &w4);
        s_off[tid] = o;
        s_wt[tid]  = w4;
    }
    __syncthreads();

    const size_t outbase = (size_t)b * (CC * NS);
    for (int c0 = 0; c0 < CC; c0 += 256) {
        const int cterm = (c0 + tid) * (HF * WF);
        for (int s = 0; s < NS; ++s) {
            int4   o = s_off[s];
            float4 w = s_wt[s];
            float v = src[o.x + cterm] * w.x + src[o.y + cterm] * w.y +
                      src[o.z + cterm] * w.z + src[o.w + cterm] * w.w;
            tile[s * 257 + tid] = v;
        }
        __syncthreads();
        const size_t ob = outbase + (size_t)c0 * NS;
        for (int k = tid; k < 256 * NS; k += 256) {
            int cl = k / NS;
            int s  = k - cl * NS;
            out[ob + k] = tile[s * 257 + cl];
        }
        __syncthreads();
    }
}

extern "C" void kernel_launch(void* const* d_in, const int* in_sizes, int n_in,
                              void* d_out, int out_size, void* d_ws, size_t ws_size,
                              hipStream_t stream) {
    const float* feats = (const float*)d_in[0];
    const float* boxes = (const float*)d_in[1];
    const int*   ih    = (const int*)d_in[2];
    const int*   iw    = (const int*)d_in[3];
    float*       out   = (float*)d_out;
    const int B = in_sizes[1] / 4;

    const size_t tf_bytes = (size_t)CC * HF * WF * sizeof(float);  // 32 MiB
    const size_t need = tf_bytes + (size_t)B * sizeof(int) + (size_t)NBINS * sizeof(int);
    if (ws_size >= need) {
        float* tf   = (float*)d_ws;
        int*   perm = (int*)((char*)d_ws + tf_bytes);
        int*   hist = (int*)((char*)d_ws + tf_bytes + (size_t)B * sizeof(int));
        dim3 tb(32, 8);
        dim3 tg((HF * WF) / 32, CC / 32);
        transpose_feats<<<tg, tb, 0, stream>>>(feats, tf);
        hist_zero<<<NBINS / 256, 256, 0, stream>>>(hist);
        hist_count<<<(B + 255) / 256, 256, 0, stream>>>(boxes, ih, iw, B, hist);
        hist_scan<<<1, 256, 0, stream>>>(hist);
        scatter_perm<<<(B + 255) / 256, 256, 0, stream>>>(boxes, ih, iw, B, hist, perm);
        roi_pool_v10<<<NSLICE * B, 256, 0, stream>>>(tf, boxes, ih, iw, perm, B, out);
    } else {
        roi_pool_fb<<<B, 256, 0, stream>>>(feats, boxes, ih, iw, out);
    }
}